// Round 2
// 338.753 us; speedup vs baseline: 1.0007x; 1.0007x over previous
//
#include <hip/hip_runtime.h>

#define B 256
#define S 24
#define D 256
#define N 8192
#define EPSF 1e-8f

// clang-native 16B vector type (__builtin_nontemporal_* rejects HIP's
// struct-based float4).
typedef float vfloat4 __attribute__((ext_vector_type(4)));

// One block per output row (b, i). 512 threads x 16 floats/thread = N=8192.
//
// Traffic is algorithmically minimal (~415 MB -> ~66 us floor at 6.3 TB/s):
// every patch row read exactly once, every output row written once. Zero
// reuse -> nt loads/stores bypass L2 allocation.
//
// R5 changes vs R4 (339 us, kernel itself <126 us per rocprof top-5):
//  - clusters row read via wave-uniform scalar loads (s_load through K$):
//    removes the LDS staging + leading __syncthreads that serialized every
//    block's prologue before the first patch load could issue.
//  - m==0 fast path (~36% of blocks): store the constant 1/N row directly,
//    skip the accumulate/shuffle-reduce/barrier machinery.
//  - loop condition popc -> (rem & rem-1) scalar trim.
// R6: identical resubmit — R5's bench was an infra failure (container), no
//     hardware signal received.
__global__ __launch_bounds__(512) void slot_merge_kernel(
    const float* __restrict__ slots,     // [B,S,D]
    const float* __restrict__ patch,     // [B,S,N]
    const int*   __restrict__ clusters,  // [B,S]
    float* __restrict__ out_slots,       // [B,S,D]
    float* __restrict__ out_patch,       // [B,S,N]
    float* __restrict__ out_nums)        // [B] (written as float)
{
    const int blk = blockIdx.x;
    const int b   = blk / S;
    const int i   = blk % S;   // cluster id this block produces
    const int tid = threadIdx.x;

    // ---- membership bitmask from wave-uniform scalar loads (no LDS, no
    //      barrier). Index is block-uniform -> compiler scalarizes to
    //      s_load; all lanes compute identical values. ----
    const int* __restrict__ crow = clusters + b * S;
    unsigned mask = 0u, present = 0u;
    #pragma unroll
    for (int j = 0; j < S; ++j) {
        const int cj = crow[j];
        mask    |= (cj == i) ? (1u << j) : 0u;
        present |= 1u << cj;
    }
    mask = __builtin_amdgcn_readfirstlane((int)mask);
    const int m = __popc(mask);

    vfloat4* __restrict__ orow = (vfloat4*)(out_patch + ((size_t)b * S + i) * N);

    // ---- slot_nums[b]: number of distinct clusters present ----
    if (i == 0 && tid == 0) {
        out_nums[b] = (float)__popc(present);
    }

    // ---- empty-cluster fast path (block-uniform branch, ~36% of blocks):
    //      out_patch row = EPS / (N*EPS) = 1/N (same value as the generic
    //      path up to last-ulp rounding); out_slots row = 0. ----
    if (mask == 0u) {
        const float v = EPSF / ((float)N * EPSF);
        const vfloat4 vv = {v, v, v, v};
        #pragma unroll
        for (int k = 0; k < 4; ++k)
            __builtin_nontemporal_store(vv, &orow[tid + k * 512]);
        if (tid < D) out_slots[((size_t)b * S + i) * D + tid] = 0.f;
        return;
    }

    // ---- slots accumulation issued FIRST so its loads overlap the patch
    //      read burst instead of sitting latency-exposed at the kernel tail.
    //      Threads 0..255 each own one d; waves 4..7 skip (wave-granular). ----
    float sacc = 0.f;
    if (tid < D) {
        unsigned rem2 = mask;
        while (rem2) {
            const int j = __builtin_ctz(rem2); rem2 &= rem2 - 1u;
            sacc += slots[((size_t)b * S + j) * D + tid];
        }
    }

    // ---- patch_attn: acc[n] = EPS + sum_{j: cl[j]==i} patch[b,j,n] ----
    vfloat4 acc[4];
    #pragma unroll
    for (int k = 0; k < 4; ++k) acc[k] = (vfloat4)(EPSF);

    const vfloat4* __restrict__ base = (const vfloat4*)(patch + (size_t)b * S * N);

    unsigned rem = mask;
    while (rem & (rem - 1u)) {   // two member rows per iteration
        const int j0 = __builtin_ctz(rem); rem &= rem - 1u;
        const int j1 = __builtin_ctz(rem); rem &= rem - 1u;
        const vfloat4* __restrict__ r0 = base + (size_t)j0 * (N / 4);
        const vfloat4* __restrict__ r1 = base + (size_t)j1 * (N / 4);
        vfloat4 v0[4], v1[4];
        #pragma unroll
        for (int k = 0; k < 4; ++k) v0[k] = __builtin_nontemporal_load(&r0[tid + k * 512]);
        #pragma unroll
        for (int k = 0; k < 4; ++k) v1[k] = __builtin_nontemporal_load(&r1[tid + k * 512]);
        #pragma unroll
        for (int k = 0; k < 4; ++k) acc[k] += v0[k] + v1[k];
    }
    if (rem) {  // odd leftover row
        const int j0 = __builtin_ctz(rem);
        const vfloat4* __restrict__ r0 = base + (size_t)j0 * (N / 4);
        vfloat4 v0[4];
        #pragma unroll
        for (int k = 0; k < 4; ++k) v0[k] = __builtin_nontemporal_load(&r0[tid + k * 512]);
        #pragma unroll
        for (int k = 0; k < 4; ++k) acc[k] += v0[k];
    }

    // ---- row total = sum_n acc[n] (each element already includes +EPS) ----
    float lsum = 0.f;
    #pragma unroll
    for (int k = 0; k < 4; ++k) lsum += acc[k].x + acc[k].y + acc[k].z + acc[k].w;

    #pragma unroll
    for (int off = 32; off > 0; off >>= 1) lsum += __shfl_down(lsum, off, 64);
    __shared__ float wsum[8];
    if ((tid & 63) == 0) wsum[tid >> 6] = lsum;
    __syncthreads();
    float total = 0.f;
    #pragma unroll
    for (int w = 0; w < 8; ++w) total += wsum[w];
    const float inv = 1.0f / total;

    #pragma unroll
    for (int k = 0; k < 4; ++k) {
        vfloat4 v = acc[k] * inv;
        __builtin_nontemporal_store(v, &orow[tid + k * 512]);
    }

    // ---- slots epilogue: mean over members ----
    if (tid < D) {
        out_slots[((size_t)b * S + i) * D + tid] = sacc / ((float)m + EPSF);
    }
}

extern "C" void kernel_launch(void* const* d_in, const int* in_sizes, int n_in,
                              void* d_out, int out_size, void* d_ws, size_t ws_size,
                              hipStream_t stream) {
    const float* slots    = (const float*)d_in[0];
    const float* patch    = (const float*)d_in[1];
    const int*   clusters = (const int*)d_in[2];

    float* out       = (float*)d_out;
    float* out_slots = out;                                          // B*S*D
    float* out_patch = out + (size_t)B * S * D;                      // B*S*N
    float* out_nums  = out + (size_t)B * S * D + (size_t)B * S * N;  // B

    slot_merge_kernel<<<B * S, 512, 0, stream>>>(
        slots, patch, clusters, out_slots, out_patch, out_nums);
}